// Round 6
// baseline (137.260 us; speedup 1.0000x reference)
//
#include <hip/hip_runtime.h>
#include <hip/hip_bf16.h>
#include <stdint.h>

#define NPTS 4096
#define NB   4
#define KNN  32
#define NKPT 15

// workspace byte offsets (all 256B-aligned)
#define OFF_IDX      0ULL            // 4*4096*32*4          = 2,097,152
#define OFF_FEAT0    2097152ULL      // 4*4097*64*4          = 4,195,328
#define OFF_WEIGHTED 6292480ULL      // 16384*960*2 (bf16)   = 31,457,280
#define OFF_HO       37749760ULL     // 16384*128*4          = 8,388,608
#define OFF_W1P      46138368ULL     // 32,768
#define OFF_W2P      46171136ULL     // 32,768
#define OFF_KPWP     46203904ULL     // 960*64*2 = 122,880 (end 46,326,784)

// d_out float offsets
#define OUT_OFF_OUT  0
#define OUT_OFF_KP   1048576
#define OUT_OFF_FUSE 1048621

// LDS unit-index XOR swizzle (16B units)
#define SBU(u) ((u) ^ (((u) >> 3) & 7))

typedef __attribute__((ext_vector_type(8))) short short8v;  // 8 bf16 (4 VGPRs)
typedef __attribute__((ext_vector_type(4))) float f32x4;    // MFMA C/D

__device__ __forceinline__ unsigned short bf16b(float f) {
  __hip_bfloat16 h = __float2bfloat16(f);
  return *(unsigned short*)&h;
}
__device__ __forceinline__ unsigned pkbf(float lo, float hi) {
  return (unsigned)bf16b(lo) | ((unsigned)bf16b(hi) << 16);
}

// ---------------- K012: neighbor search + feat0 + prepacks, one launch ----------------
__global__ __launch_bounds__(256) void k012(const float* __restrict__ pos,
                                            const float* __restrict__ feat,
                                            const float* __restrict__ cb_w,
                                            const float* __restrict__ cb_b,
                                            const float* __restrict__ f1_w,
                                            const float* __restrict__ f2_w,
                                            const float* __restrict__ kpw,
                                            const float* __restrict__ kp_pos,
                                            int* __restrict__ idx_ws,
                                            float* __restrict__ feat0,
                                            unsigned short* __restrict__ w1p,
                                            unsigned short* __restrict__ w2p,
                                            unsigned short* __restrict__ kpwp,
                                            float* __restrict__ out_kp) {
  __shared__ float cbt[64 * 65];
  const int blk = blockIdx.x;
  if (blk < 4096) {
    const int w = threadIdx.x >> 6, lane = threadIdx.x & 63;
    const int pt = blk * 4 + w;
    const int b = pt >> 12, n = pt & 4095;
    const float* px = pos + (size_t)b * 3 * NPTS;
    const double x0 = (double)px[n], y0 = (double)px[NPTS + n], z0 = (double)px[2 * NPTS + n];
    const double ssrc = x0 * x0 + y0 * y0 + z0 * z0;
    const double RAD = 0.1 * 2.0;
    const double R2 = RAD * RAD;
    int cnt = 0;
    int* op = idx_ws + (size_t)pt * KNN;
    for (int ch = 0; ch < 64; ++ch) {
      const int j = ch * 64 + lane;
      const double xj = (double)px[j], yj = (double)px[NPTS + j], zj = (double)px[2 * NPTS + j];
      const double dot  = x0 * xj + y0 * yj + z0 * zj;
      const double sdst = xj * xj + yj * yj + zj * zj;
      const double sq = -2.0 * dot + ssrc + sdst;
      const bool keep = !(sq > R2);
      const unsigned long long m = __ballot(keep);
      if (keep) {
        const int p = cnt + (int)__popcll(m & ((1ULL << lane) - 1ULL));
        if (p < KNN) op[p] = j;
      }
      cnt += (int)__popcll(m);
      if (cnt >= KNN) break;
    }
    const int s = cnt + lane;
    if (s < KNN) op[s] = NPTS;
    return;
  }
  if (blk < 8192) {
    const int t = threadIdx.x;
    #pragma unroll
    for (int q = 0; q < 16; ++q) {
      const int idx = q * 256 + t;
      const int d = idx >> 6, c = idx & 63;
      cbt[c * 65 + d] = cb_w[idx];
    }
    __syncthreads();
    const int ptl = t >> 6, d = t & 63;
    const int pt = (blk - 4096) * 4 + ptl;
    const int b = pt >> 12, n = pt & 4095;
    const float* fp = feat + (size_t)b * 64 * NPTS + n;
    float acc = 0.f;
    #pragma unroll
    for (int c = 0; c < 64; ++c) acc = fmaf(cbt[c * 65 + d], fp[(size_t)c * NPTS], acc);
    acc += cb_b[d];
    feat0[((size_t)b * (NPTS + 1) + n) * 64 + d] = acc;
    return;
  }
  int t = (blk - 8192) * 256 + threadIdx.x;
  if (t < 32768) {
    const int w = t >> 14;
    const int i = t & 16383;
    const int j = i & 7, l = (i >> 3) & 63, kc = (i >> 9) & 3, ot = i >> 11;
    const int o = ot * 16 + (l & 15);
    const int k = kc * 32 + (l >> 4) * 8 + j;
    const float* src = w ? f2_w : f1_w;
    unsigned short* dst = w ? w2p : w1p;
    dst[i] = bf16b(src[o * 128 + k]);
    return;
  }
  t -= 32768;
  if (t < 61440) {
    const int j = t & 7, l = (t >> 3) & 63, nt = (t >> 9) & 3, kc = t >> 11;
    const int k = kc * 32 + (l >> 4) * 8 + j;
    const int d = nt * 16 + (l & 15);
    kpwp[t] = bf16b(kpw[(size_t)k * 64 + d]);
    return;
  }
  t -= 61440;
  if (t < NB * 64) { int b = t >> 6, d = t & 63; feat0[((size_t)b * (NPTS + 1) + NPTS) * 64 + d] = 0.f; return; }
  t -= NB * 64;
  if (t < 45) out_kp[t] = kp_pos[t];
}

// ---------------- K3: gather + kernel-point weights -> weighted bf16 [16384][960] ----------------
// 256 threads = 4 waves, 4 points per block (better MLP than 1-wave blocks).
__global__ __launch_bounds__(256) void k3_weighted(const float* __restrict__ pos,
                                                   const int* __restrict__ idx_ws,
                                                   const float* __restrict__ feat0,
                                                   const float* __restrict__ kp_pos,
                                                   unsigned short* __restrict__ wbf) {
  __shared__ int   nidx[4][KNN];
  __shared__ float npx[4][KNN], npy[4][KNN], npz[4][KNN];
  __shared__ float kp[48];
  __shared__ float wl[4][KNN * 16];
  const int wv = threadIdx.x >> 6, lane = threadIdx.x & 63;
  const int pt = blockIdx.x * 4 + wv;
  const int b = pt >> 12;
  if (threadIdx.x < 45) kp[threadIdx.x] = kp_pos[threadIdx.x];
  if (lane < KNN) {
    const int ki = idx_ws[(size_t)pt * KNN + lane];
    nidx[wv][lane] = ki;
    const bool v = ki < NPTS;
    const float* px = pos + (size_t)b * 3 * NPTS;
    npx[wv][lane] = v ? px[ki] : 1000000.0f;
    npy[wv][lane] = v ? px[NPTS + ki] : 1000000.0f;
    npz[wv][lane] = v ? px[2 * NPTS + ki] : 1000000.0f;
  }
  __syncthreads();
  #pragma unroll
  for (int r = 0; r < 8; ++r) {
    const int i = r * 64 + lane;
    const int k = i >> 4, p = i & 15;
    float wvv = 0.f;
    if (p < 15) {
      const float dx = npx[wv][k] - kp[p];
      const float dy = npy[wv][k] - kp[15 + p];
      const float dz = npz[wv][k] - kp[30 + p];
      const float d2 = dx * dx + dy * dy + dz * dz;
      wvv = fmaxf(1.0f - sqrtf(d2) / 1.2f, 0.f);
    }
    wl[wv][i] = wvv;
  }
  __syncthreads();
  float acc[16];
  #pragma unroll
  for (int p = 0; p < 16; ++p) acc[p] = 0.f;
  const float* f0 = feat0 + (size_t)b * (NPTS + 1) * 64 + lane;
  for (int k = 0; k < KNN; ++k) {
    const float f = f0[(size_t)nidx[wv][k] * 64];
    #pragma unroll
    for (int q = 0; q < 4; ++q) {
      const float4 w4 = *(const float4*)&wl[wv][k * 16 + q * 4];
      acc[q * 4 + 0] = fmaf(w4.x, f, acc[q * 4 + 0]);
      acc[q * 4 + 1] = fmaf(w4.y, f, acc[q * 4 + 1]);
      acc[q * 4 + 2] = fmaf(w4.z, f, acc[q * 4 + 2]);
      acc[q * 4 + 3] = fmaf(w4.w, f, acc[q * 4 + 3]);
    }
  }
  unsigned short* wp = wbf + (size_t)pt * NKPT * 64 + lane;
  #pragma unroll
  for (int p = 0; p < 15; ++p) wp[(size_t)p * 64] = bf16b(acc[p]);
}

// ---------------- K45: kpconv MFMA -> out (+feat residual) -> hO = W1b@out + b1 ----------------
__global__ __launch_bounds__(256) void k45(const unsigned short* __restrict__ wbf,
                                           const unsigned short* __restrict__ kpwp,
                                           const float* __restrict__ kp_bias,
                                           const float* __restrict__ ce_w,
                                           const float* __restrict__ ce_b,
                                           const float* __restrict__ feat,
                                           const unsigned short* __restrict__ w1p,
                                           const float* __restrict__ f1_b,
                                           float* __restrict__ out,
                                           float* __restrict__ hO) {
  __shared__ float r0[64 * 65];
  __shared__ float cwt[64 * 64];
  __shared__ unsigned short outT[64 * 74];
  const int t = threadIdx.x;
  const int b = blockIdx.x >> 6;
  const int n0 = (blockIdx.x & 63) * 64;
  const int wv = t >> 6, lane = t & 63;
  #pragma unroll
  for (int q = 0; q < 16; ++q) {
    const int idx = q * 256 + t;
    cwt[idx] = ce_w[(idx & 63) * 64 + (idx >> 6)];
  }
  const short8v* kf = (const short8v*)kpwp;
  f32x4 acc[4];
  #pragma unroll
  for (int nt = 0; nt < 4; ++nt) acc[nt] = (f32x4){0.f, 0.f, 0.f, 0.f};
  const int m0 = b * 4096 + n0 + wv * 16;
  const unsigned short* ap = wbf + (size_t)(m0 + (lane & 15)) * 960 + (lane >> 4) * 8;
  #pragma unroll 6
  for (int kc = 0; kc < 30; ++kc) {
    const short8v a = *(const short8v*)&ap[kc * 32];
    #pragma unroll
    for (int nt = 0; nt < 4; ++nt)
      acc[nt] = __builtin_amdgcn_mfma_f32_16x16x32_bf16(a, kf[(kc * 4 + nt) * 64 + lane], acc[nt], 0, 0, 0);
  }
  const int rl = wv * 16 + (lane >> 4) * 4;
  #pragma unroll
  for (int nt = 0; nt < 4; ++nt) {
    const int d = nt * 16 + (lane & 15);
    const float bv = kp_bias[d];
    #pragma unroll
    for (int r = 0; r < 4; ++r)
      r0[(rl + r) * 65 + d] = fmaxf(acc[nt][r] + bv, 0.f);
  }
  __syncthreads();
  const int nl = t & 63, og = t >> 6;
  float facc[16];
  #pragma unroll
  for (int j = 0; j < 16; ++j) facc[j] = 0.f;
  for (int c = 0; c < 64; ++c) {
    const float x = r0[nl * 65 + c];
    #pragma unroll
    for (int q = 0; q < 4; ++q) {
      const float4 w4 = *(const float4*)&cwt[c * 64 + og * 16 + q * 4];
      facc[q * 4 + 0] = fmaf(w4.x, x, facc[q * 4 + 0]);
      facc[q * 4 + 1] = fmaf(w4.y, x, facc[q * 4 + 1]);
      facc[q * 4 + 2] = fmaf(w4.z, x, facc[q * 4 + 2]);
      facc[q * 4 + 3] = fmaf(w4.w, x, facc[q * 4 + 3]);
    }
  }
  #pragma unroll
  for (int q = 0; q < 4; ++q) {
    const float4 cb4 = *(const float4*)&ce_b[og * 16 + q * 4];
    const float cbv[4] = {cb4.x, cb4.y, cb4.z, cb4.w};
    #pragma unroll
    for (int j = 0; j < 4; ++j) {
      const int o = og * 16 + q * 4 + j;
      const float fv = feat[((size_t)b * 64 + o) * 4096 + n0 + nl];
      const float v = fmaxf((facc[q * 4 + j] + cbv[j]) + fv, 0.f);
      out[((size_t)b * 64 + o) * 4096 + n0 + nl] = v;
      outT[o * 74 + nl] = bf16b(v);
    }
  }
  __syncthreads();
  const short8v* w1f = (const short8v*)w1p;
  f32x4 hacc[8];
  #pragma unroll
  for (int ot = 0; ot < 8; ++ot) hacc[ot] = (f32x4){0.f, 0.f, 0.f, 0.f};
  const int nw = lane & 15;
  #pragma unroll
  for (int kc2 = 0; kc2 < 2; ++kc2) {
    short8v bfr;
    #pragma unroll
    for (int j = 0; j < 8; ++j)
      bfr[j] = (short)outT[(kc2 * 32 + (lane >> 4) * 8 + j) * 74 + wv * 16 + nw];
    #pragma unroll
    for (int ot = 0; ot < 8; ++ot)
      hacc[ot] = __builtin_amdgcn_mfma_f32_16x16x32_bf16(w1f[(ot * 4 + 2 + kc2) * 64 + lane], bfr, hacc[ot], 0, 0, 0);
  }
  const int rb = (lane >> 4) * 4;
  float* hp = hO + ((size_t)b * 4096 + n0 + wv * 16 + nw) * 128;
  #pragma unroll
  for (int ot = 0; ot < 8; ++ot) {
    const float4 b1 = *(const float4*)&f1_b[ot * 16 + rb];
    const float bv[4] = {b1.x, b1.y, b1.z, b1.w};
    #pragma unroll
    for (int r = 0; r < 4; ++r)
      hp[ot * 16 + rb + r] = hacc[ot][r] + bv[r];
  }
}

// ---------------- K6: fuse via bf16 MFMA; coalesced store epilogue via LDS transpose ----------------
__global__ __launch_bounds__(256, 2) void k6_fuse(const unsigned short* __restrict__ wbf,
                                                  const float* __restrict__ hO,
                                                  const unsigned short* __restrict__ w1p,
                                                  const unsigned short* __restrict__ w2p,
                                                  const float* __restrict__ f2_b,
                                                  float* __restrict__ fuse) {
  __shared__ __attribute__((aligned(16))) unsigned short SB[16384];  // 32 KB
  __shared__ __attribute__((aligned(16))) float hOS[12 * 128];       // 6 KB
  const int t = threadIdx.x;
  const int blk = blockIdx.x;
  const int b = blk / 480;
  const int ml0 = (blk - b * 480) * 128;
  const size_t M0 = (size_t)blk * 128;
  const int wv = t >> 6, lane = t & 63;
  const short8v* w1f = (const short8v*)w1p;
  const short8v* w2f = (const short8v*)w2p;

  // early W1 top-half fragment loads (16)
  short8v w1r[16];
  #pragma unroll
  for (int ot = 0; ot < 8; ++ot)
    #pragma unroll
    for (int kc = 0; kc < 2; ++kc)
      w1r[ot * 2 + kc] = w1f[(ot * 4 + kc) * 64 + lane];

  // stage Xw (c=0..63): bf16 bit-copy from weighted
  #pragma unroll
  for (int q = 0; q < 4; ++q) {
    const int chunk = q * 256 + t;
    const int m = chunk >> 3, a = chunk & 7;
    const uint4 pk = *(const uint4*)&wbf[(M0 + m) * 64 + a * 8];
    const int kc = a >> 2, hi = a & 3;
    const int u = ((m >> 4) * 4 + kc) * 64 + hi * 16 + (m & 15);
    *(uint4*)&SB[SBU(u) * 8] = pk;
  }
  // stage hO rows for this tile's n-range
  const int nmin = ml0 / 15;
  #pragma unroll
  for (int q = 0; q < 6; ++q) {
    const int idx = q * 256 + t;
    const int row = idx >> 7, o = idx & 127;
    int n = nmin + row;
    if (n > 4095) n = 4095;
    hOS[idx] = hO[((size_t)b * 4096 + n) * 128 + o];
  }
  __syncthreads();

  // this wave's Xw B-fragments (K=64: kc 0,1)
  short8v xf[4];
  #pragma unroll
  for (int mt = 0; mt < 2; ++mt)
    #pragma unroll
    for (int kc = 0; kc < 2; ++kc) {
      const int u = ((wv * 2 + mt) * 4 + kc) * 64 + lane;
      xf[mt * 2 + kc] = *(const short8v*)&SB[SBU(u) * 8];
    }

  const int rb = (lane >> 4) * 4;
  const int dnA = (ml0 + wv * 32 + (lane & 15)) / 15 - nmin;
  const int dnB = (ml0 + wv * 32 + 16 + (lane & 15)) / 15 - nmin;
  f32x4 acc[8][2];
  #pragma unroll
  for (int ot = 0; ot < 8; ++ot) {
    acc[ot][0] = *(const f32x4*)&hOS[dnA * 128 + ot * 16 + rb];
    acc[ot][1] = *(const f32x4*)&hOS[dnB * 128 + ot * 16 + rb];
  }
  // stage 1: acc += W1a @ Xw  (K=64)
  #pragma unroll
  for (int kc = 0; kc < 2; ++kc) {
    #pragma unroll
    for (int ot = 0; ot < 8; ++ot) {
      acc[ot][0] = __builtin_amdgcn_mfma_f32_16x16x32_bf16(w1r[ot * 2 + kc], xf[kc],     acc[ot][0], 0, 0, 0);
      acc[ot][1] = __builtin_amdgcn_mfma_f32_16x16x32_bf16(w1r[ot * 2 + kc], xf[2 + kc], acc[ot][1], 0, 0, 0);
    }
  }
  // issue W2 loads — latency covered by H epilogue
  short8v w2r[32];
  #pragma unroll
  for (int i = 0; i < 32; ++i) w2r[i] = w2f[i * 64 + lane];

  // H epilogue (relu; b1 folded into hO) -> wave's own SB region
  #pragma unroll
  for (int ot = 0; ot < 8; ++ot) {
    const int o0 = ot * 16 + rb;
    const int kc = o0 >> 5, hi = (o0 >> 3) & 3, j0 = o0 & 7;
    #pragma unroll
    for (int mt = 0; mt < 2; ++mt) {
      const f32x4 h = acc[ot][mt];
      const float h0 = fmaxf(h[0], 0.f);
      const float h1 = fmaxf(h[1], 0.f);
      const float h2 = fmaxf(h[2], 0.f);
      const float h3 = fmaxf(h[3], 0.f);
      const int u = ((wv * 2 + mt) * 4 + kc) * 64 + hi * 16 + (lane & 15);
      uint2 pk;
      pk.x = pkbf(h0, h1);
      pk.y = pkbf(h2, h3);
      *(uint2*)&SB[SBU(u) * 8 + j0] = pk;
    }
  }
  // read H fragments (K=128)
  short8v hf[8];
  #pragma unroll
  for (int mt = 0; mt < 2; ++mt)
    #pragma unroll
    for (int kc = 0; kc < 4; ++kc) {
      const int u = ((wv * 2 + mt) * 4 + kc) * 64 + lane;
      hf[mt * 4 + kc] = *(const short8v*)&SB[SBU(u) * 8];
    }
  __syncthreads();  // all hf reads done -> SB reusable as fp32 scratch
  // stage 2
  #pragma unroll
  for (int ot = 0; ot < 8; ++ot) {
    acc[ot][0] = (f32x4){0.f, 0.f, 0.f, 0.f};
    acc[ot][1] = (f32x4){0.f, 0.f, 0.f, 0.f};
  }
  #pragma unroll
  for (int kc = 0; kc < 4; ++kc) {
    #pragma unroll
    for (int ot = 0; ot < 8; ++ot) {
      acc[ot][0] = __builtin_amdgcn_mfma_f32_16x16x32_bf16(w2r[ot * 4 + kc], hf[kc],     acc[ot][0], 0, 0, 0);
      acc[ot][1] = __builtin_amdgcn_mfma_f32_16x16x32_bf16(w2r[ot * 4 + kc], hf[4 + kc], acc[ot][1], 0, 0, 0);
    }
  }
  // F epilogue: LDS transpose (SB aliased as fp32, stride 132) -> contiguous dword stores
  float* SBf = (float*)SB;  // 32 rows x 132 floats = 16,896 B <= 32 KB
  const int colw = wv * 32 + (lane & 15);
  float* fblk = fuse + (size_t)b * 128 * 61440 + ml0;
  #pragma unroll
  for (int p = 0; p < 4; ++p) {
    #pragma unroll
    for (int oi = 0; oi < 2; ++oi) {
      const int ot = p * 2 + oi;
      const int o0 = ot * 16 + rb;
      const float4 b2 = *(const float4*)&f2_b[o0];
      const float bv[4] = {b2.x, b2.y, b2.z, b2.w};
      #pragma unroll
      for (int mt = 0; mt < 2; ++mt) {
        const f32x4 v = acc[ot][mt];
        #pragma unroll
        for (int r = 0; r < 4; ++r)
          SBf[(oi * 16 + rb + r) * 132 + colw + mt * 16] = fmaxf(v[r] + bv[r], 0.f);
      }
    }
    __syncthreads();
    // cooperative store: 32 rows x 128 cols, 256B contiguous per wave-instruction
    #pragma unroll
    for (int q = 0; q < 16; ++q) {
      const int idx = q * 256 + t;          // 0..4095
      const int row = idx >> 7, c = idx & 127;
      fblk[(size_t)(p * 32 + row) * 61440 + c] = SBf[row * 132 + c];
    }
    __syncthreads();
  }
}

extern "C" void kernel_launch(void* const* d_in, const int* in_sizes, int n_in,
                              void* d_out, int out_size, void* d_ws, size_t ws_size,
                              hipStream_t stream) {
  const float* pos     = (const float*)d_in[0];
  const float* feat    = (const float*)d_in[1];
  const float* kp_pos  = (const float*)d_in[2];
  const float* cb_w    = (const float*)d_in[3];
  const float* cb_b    = (const float*)d_in[4];
  const float* kpw     = (const float*)d_in[5];
  const float* kp_bias = (const float*)d_in[6];
  const float* ce_w    = (const float*)d_in[7];
  const float* ce_b    = (const float*)d_in[8];
  const float* f1_w    = (const float*)d_in[9];
  const float* f1_b    = (const float*)d_in[10];
  const float* f2_w    = (const float*)d_in[11];
  const float* f2_b    = (const float*)d_in[12];
  float* out = (float*)d_out;
  char* ws = (char*)d_ws;
  int*   idx_ws   = (int*)(ws + OFF_IDX);
  float* feat0    = (float*)(ws + OFF_FEAT0);
  unsigned short* wbf  = (unsigned short*)(ws + OFF_WEIGHTED);
  float* hO       = (float*)(ws + OFF_HO);
  unsigned short* w1p  = (unsigned short*)(ws + OFF_W1P);
  unsigned short* w2p  = (unsigned short*)(ws + OFF_W2P);
  unsigned short* kpwp = (unsigned short*)(ws + OFF_KPWP);

  k012<<<8562, 256, 0, stream>>>(pos, feat, cb_w, cb_b, f1_w, f2_w, kpw, kp_pos,
                                 idx_ws, feat0, w1p, w2p, kpwp, out + OUT_OFF_KP);
  k3_weighted<<<4096, 256, 0, stream>>>(pos, idx_ws, feat0, kp_pos, wbf);
  k45<<<256, 256, 0, stream>>>(wbf, kpwp, kp_bias, ce_w, ce_b, feat, w1p, f1_b,
                               out + OUT_OFF_OUT, hO);
  k6_fuse<<<1920, 256, 0, stream>>>(wbf, hO, w1p, w2p, f2_b, out + OUT_OFF_FUSE);
}

// Round 7
// 137.109 us; speedup vs baseline: 1.0011x; 1.0011x over previous
//
#include <hip/hip_runtime.h>
#include <hip/hip_bf16.h>
#include <stdint.h>

#define NPTS 4096
#define NB   4
#define KNN  32
#define NKPT 15

// workspace byte offsets (all 256B-aligned)
#define OFF_IDX      0ULL            // 4*4096*32*4          = 2,097,152
#define OFF_FEAT0    2097152ULL      // 4*4097*64*4          = 4,195,328
#define OFF_WEIGHTED 6292480ULL      // 16384*960*2 (bf16)   = 31,457,280
#define OFF_HO       37749760ULL     // 16384*128*2 (bf16)   = 4,194,304
#define OFF_W1P      41944064ULL     // 32,768
#define OFF_W2P      41976832ULL     // 32,768
#define OFF_KPWP     42009600ULL     // 960*64*2 = 122,880 (end 42,132,480)

// d_out float offsets
#define OUT_OFF_OUT  0
#define OUT_OFF_KP   1048576
#define OUT_OFF_FUSE 1048621

// LDS unit-index XOR swizzle (16B units)
#define SBU(u) ((u) ^ (((u) >> 3) & 7))

typedef __attribute__((ext_vector_type(8))) short short8v;  // 8 bf16 (4 VGPRs)
typedef __attribute__((ext_vector_type(4))) float f32x4;    // MFMA C/D

__device__ __forceinline__ unsigned short bf16b(float f) {
  __hip_bfloat16 h = __float2bfloat16(f);
  return *(unsigned short*)&h;
}
__device__ __forceinline__ unsigned pkbf(float lo, float hi) {
  return (unsigned)bf16b(lo) | ((unsigned)bf16b(hi) << 16);
}
__device__ __forceinline__ float bflo(unsigned u) { return __uint_as_float(u << 16); }
__device__ __forceinline__ float bfhi(unsigned u) { return __uint_as_float(u & 0xffff0000u); }

// ---------------- K012: neighbor search + feat0 + prepacks, one launch ----------------
__global__ __launch_bounds__(256) void k012(const float* __restrict__ pos,
                                            const float* __restrict__ feat,
                                            const float* __restrict__ cb_w,
                                            const float* __restrict__ cb_b,
                                            const float* __restrict__ f1_w,
                                            const float* __restrict__ f2_w,
                                            const float* __restrict__ kpw,
                                            const float* __restrict__ kp_pos,
                                            int* __restrict__ idx_ws,
                                            float* __restrict__ feat0,
                                            unsigned short* __restrict__ w1p,
                                            unsigned short* __restrict__ w2p,
                                            unsigned short* __restrict__ kpwp,
                                            float* __restrict__ out_kp) {
  __shared__ float cbt[64 * 65];
  const int blk = blockIdx.x;
  if (blk < 4096) {
    const int w = threadIdx.x >> 6, lane = threadIdx.x & 63;
    const int pt = blk * 4 + w;
    const int b = pt >> 12, n = pt & 4095;
    const float* px = pos + (size_t)b * 3 * NPTS;
    const double x0 = (double)px[n], y0 = (double)px[NPTS + n], z0 = (double)px[2 * NPTS + n];
    const double ssrc = x0 * x0 + y0 * y0 + z0 * z0;
    const double RAD = 0.1 * 2.0;
    const double R2 = RAD * RAD;
    int cnt = 0;
    int* op = idx_ws + (size_t)pt * KNN;
    for (int ch = 0; ch < 64; ++ch) {
      const int j = ch * 64 + lane;
      const double xj = (double)px[j], yj = (double)px[NPTS + j], zj = (double)px[2 * NPTS + j];
      const double dot  = x0 * xj + y0 * yj + z0 * zj;
      const double sdst = xj * xj + yj * yj + zj * zj;
      const double sq = -2.0 * dot + ssrc + sdst;
      const bool keep = !(sq > R2);
      const unsigned long long m = __ballot(keep);
      if (keep) {
        const int p = cnt + (int)__popcll(m & ((1ULL << lane) - 1ULL));
        if (p < KNN) op[p] = j;
      }
      cnt += (int)__popcll(m);
      if (cnt >= KNN) break;
    }
    const int s = cnt + lane;
    if (s < KNN) op[s] = NPTS;
    return;
  }
  if (blk < 8192) {
    const int t = threadIdx.x;
    #pragma unroll
    for (int q = 0; q < 16; ++q) {
      const int idx = q * 256 + t;
      const int d = idx >> 6, c = idx & 63;
      cbt[c * 65 + d] = cb_w[idx];
    }
    __syncthreads();
    const int ptl = t >> 6, d = t & 63;
    const int pt = (blk - 4096) * 4 + ptl;
    const int b = pt >> 12, n = pt & 4095;
    const float* fp = feat + (size_t)b * 64 * NPTS + n;
    float acc = 0.f;
    #pragma unroll
    for (int c = 0; c < 64; ++c) acc = fmaf(cbt[c * 65 + d], fp[(size_t)c * NPTS], acc);
    acc += cb_b[d];
    feat0[((size_t)b * (NPTS + 1) + n) * 64 + d] = acc;
    return;
  }
  int t = (blk - 8192) * 256 + threadIdx.x;
  if (t < 32768) {
    const int w = t >> 14;
    const int i = t & 16383;
    const int j = i & 7, l = (i >> 3) & 63, kc = (i >> 9) & 3, ot = i >> 11;
    const int o = ot * 16 + (l & 15);
    const int k = kc * 32 + (l >> 4) * 8 + j;
    const float* src = w ? f2_w : f1_w;
    unsigned short* dst = w ? w2p : w1p;
    dst[i] = bf16b(src[o * 128 + k]);
    return;
  }
  t -= 32768;
  if (t < 61440) {
    const int j = t & 7, l = (t >> 3) & 63, nt = (t >> 9) & 3, kc = t >> 11;
    const int k = kc * 32 + (l >> 4) * 8 + j;
    const int d = nt * 16 + (l & 15);
    kpwp[t] = bf16b(kpw[(size_t)k * 64 + d]);
    return;
  }
  t -= 61440;
  if (t < NB * 64) { int b = t >> 6, d = t & 63; feat0[((size_t)b * (NPTS + 1) + NPTS) * 64 + d] = 0.f; return; }
  t -= NB * 64;
  if (t < 45) out_kp[t] = kp_pos[t];
}

// ---------------- K3: gather + kernel-point weights -> weighted bf16 [16384][960] ----------------
__global__ __launch_bounds__(256) void k3_weighted(const float* __restrict__ pos,
                                                   const int* __restrict__ idx_ws,
                                                   const float* __restrict__ feat0,
                                                   const float* __restrict__ kp_pos,
                                                   unsigned short* __restrict__ wbf) {
  __shared__ int   nidx[4][KNN];
  __shared__ float npx[4][KNN], npy[4][KNN], npz[4][KNN];
  __shared__ float kp[48];
  __shared__ float wl[4][KNN * 16];
  const int wv = threadIdx.x >> 6, lane = threadIdx.x & 63;
  const int pt = blockIdx.x * 4 + wv;
  const int b = pt >> 12;
  if (threadIdx.x < 45) kp[threadIdx.x] = kp_pos[threadIdx.x];
  if (lane < KNN) {
    const int ki = idx_ws[(size_t)pt * KNN + lane];
    nidx[wv][lane] = ki;
    const bool v = ki < NPTS;
    const float* px = pos + (size_t)b * 3 * NPTS;
    npx[wv][lane] = v ? px[ki] : 1000000.0f;
    npy[wv][lane] = v ? px[NPTS + ki] : 1000000.0f;
    npz[wv][lane] = v ? px[2 * NPTS + ki] : 1000000.0f;
  }
  __syncthreads();
  #pragma unroll
  for (int r = 0; r < 8; ++r) {
    const int i = r * 64 + lane;
    const int k = i >> 4, p = i & 15;
    float wvv = 0.f;
    if (p < 15) {
      const float dx = npx[wv][k] - kp[p];
      const float dy = npy[wv][k] - kp[15 + p];
      const float dz = npz[wv][k] - kp[30 + p];
      const float d2 = dx * dx + dy * dy + dz * dz;
      wvv = fmaxf(1.0f - sqrtf(d2) / 1.2f, 0.f);
    }
    wl[wv][i] = wvv;
  }
  __syncthreads();
  float acc[16];
  #pragma unroll
  for (int p = 0; p < 16; ++p) acc[p] = 0.f;
  const float* f0 = feat0 + (size_t)b * (NPTS + 1) * 64 + lane;
  for (int k = 0; k < KNN; ++k) {
    const float f = f0[(size_t)nidx[wv][k] * 64];
    #pragma unroll
    for (int q = 0; q < 4; ++q) {
      const float4 w4 = *(const float4*)&wl[wv][k * 16 + q * 4];
      acc[q * 4 + 0] = fmaf(w4.x, f, acc[q * 4 + 0]);
      acc[q * 4 + 1] = fmaf(w4.y, f, acc[q * 4 + 1]);
      acc[q * 4 + 2] = fmaf(w4.z, f, acc[q * 4 + 2]);
      acc[q * 4 + 3] = fmaf(w4.w, f, acc[q * 4 + 3]);
    }
  }
  unsigned short* wp = wbf + (size_t)pt * NKPT * 64 + lane;
  #pragma unroll
  for (int p = 0; p < 15; ++p) wp[(size_t)p * 64] = bf16b(acc[p]);
}

// ---------------- K45: kpconv MFMA -> out (+feat residual) -> hO(bf16) = W1b@out + b1 ----------------
__global__ __launch_bounds__(256) void k45(const unsigned short* __restrict__ wbf,
                                           const unsigned short* __restrict__ kpwp,
                                           const float* __restrict__ kp_bias,
                                           const float* __restrict__ ce_w,
                                           const float* __restrict__ ce_b,
                                           const float* __restrict__ feat,
                                           const unsigned short* __restrict__ w1p,
                                           const float* __restrict__ f1_b,
                                           float* __restrict__ out,
                                           unsigned short* __restrict__ hOb) {
  __shared__ float r0[64 * 65];
  __shared__ float cwt[64 * 64];
  __shared__ unsigned short outT[64 * 74];
  const int t = threadIdx.x;
  const int b = blockIdx.x >> 6;
  const int n0 = (blockIdx.x & 63) * 64;
  const int wv = t >> 6, lane = t & 63;
  #pragma unroll
  for (int q = 0; q < 16; ++q) {
    const int idx = q * 256 + t;
    cwt[idx] = ce_w[(idx & 63) * 64 + (idx >> 6)];
  }
  const short8v* kf = (const short8v*)kpwp;
  f32x4 acc[4];
  #pragma unroll
  for (int nt = 0; nt < 4; ++nt) acc[nt] = (f32x4){0.f, 0.f, 0.f, 0.f};
  const int m0 = b * 4096 + n0 + wv * 16;
  const unsigned short* ap = wbf + (size_t)(m0 + (lane & 15)) * 960 + (lane >> 4) * 8;
  #pragma unroll 6
  for (int kc = 0; kc < 30; ++kc) {
    const short8v a = *(const short8v*)&ap[kc * 32];
    #pragma unroll
    for (int nt = 0; nt < 4; ++nt)
      acc[nt] = __builtin_amdgcn_mfma_f32_16x16x32_bf16(a, kf[(kc * 4 + nt) * 64 + lane], acc[nt], 0, 0, 0);
  }
  const int rl = wv * 16 + (lane >> 4) * 4;
  #pragma unroll
  for (int nt = 0; nt < 4; ++nt) {
    const int d = nt * 16 + (lane & 15);
    const float bv = kp_bias[d];
    #pragma unroll
    for (int r = 0; r < 4; ++r)
      r0[(rl + r) * 65 + d] = fmaxf(acc[nt][r] + bv, 0.f);
  }
  __syncthreads();
  const int nl = t & 63, og = t >> 6;
  float facc[16];
  #pragma unroll
  for (int j = 0; j < 16; ++j) facc[j] = 0.f;
  for (int c = 0; c < 64; ++c) {
    const float x = r0[nl * 65 + c];
    #pragma unroll
    for (int q = 0; q < 4; ++q) {
      const float4 w4 = *(const float4*)&cwt[c * 64 + og * 16 + q * 4];
      facc[q * 4 + 0] = fmaf(w4.x, x, facc[q * 4 + 0]);
      facc[q * 4 + 1] = fmaf(w4.y, x, facc[q * 4 + 1]);
      facc[q * 4 + 2] = fmaf(w4.z, x, facc[q * 4 + 2]);
      facc[q * 4 + 3] = fmaf(w4.w, x, facc[q * 4 + 3]);
    }
  }
  #pragma unroll
  for (int q = 0; q < 4; ++q) {
    const float4 cb4 = *(const float4*)&ce_b[og * 16 + q * 4];
    const float cbv[4] = {cb4.x, cb4.y, cb4.z, cb4.w};
    #pragma unroll
    for (int j = 0; j < 4; ++j) {
      const int o = og * 16 + q * 4 + j;
      const float fv = feat[((size_t)b * 64 + o) * 4096 + n0 + nl];
      const float v = fmaxf((facc[q * 4 + j] + cbv[j]) + fv, 0.f);
      out[((size_t)b * 64 + o) * 4096 + n0 + nl] = v;
      outT[o * 74 + nl] = bf16b(v);
    }
  }
  __syncthreads();
  const short8v* w1f = (const short8v*)w1p;
  f32x4 hacc[8];
  #pragma unroll
  for (int ot = 0; ot < 8; ++ot) hacc[ot] = (f32x4){0.f, 0.f, 0.f, 0.f};
  const int nw = lane & 15;
  #pragma unroll
  for (int kc2 = 0; kc2 < 2; ++kc2) {
    short8v bfr;
    #pragma unroll
    for (int j = 0; j < 8; ++j)
      bfr[j] = (short)outT[(kc2 * 32 + (lane >> 4) * 8 + j) * 74 + wv * 16 + nw];
    #pragma unroll
    for (int ot = 0; ot < 8; ++ot)
      hacc[ot] = __builtin_amdgcn_mfma_f32_16x16x32_bf16(w1f[(ot * 4 + 2 + kc2) * 64 + lane], bfr, hacc[ot], 0, 0, 0);
  }
  const int rb = (lane >> 4) * 4;
  unsigned short* hp = hOb + ((size_t)b * 4096 + n0 + wv * 16 + nw) * 128;
  #pragma unroll
  for (int ot = 0; ot < 8; ++ot) {
    const int o0 = ot * 16 + rb;
    const float4 b1 = *(const float4*)&f1_b[o0];
    uint2 pk;
    pk.x = pkbf(hacc[ot][0] + b1.x, hacc[ot][1] + b1.y);
    pk.y = pkbf(hacc[ot][2] + b1.z, hacc[ot][3] + b1.w);
    *(uint2*)&hp[o0] = pk;
  }
}

// ---------------- K6: fuse via bf16 MFMA; pipelined W2 halves, no spill ----------------
__global__ __launch_bounds__(256, 2) void k6_fuse(const unsigned short* __restrict__ wbf,
                                                  const unsigned short* __restrict__ hOb,
                                                  const unsigned short* __restrict__ w1p,
                                                  const unsigned short* __restrict__ w2p,
                                                  const float* __restrict__ f2_b,
                                                  float* __restrict__ fuse) {
  __shared__ __attribute__((aligned(16))) unsigned short SB[16384];  // 32 KB
  __shared__ __attribute__((aligned(8))) unsigned short hOS[12 * 128];  // 3 KB
  const int t = threadIdx.x;
  const int blk = blockIdx.x;
  const int b = blk / 480;
  const int ml0 = (blk - b * 480) * 128;
  const size_t M0 = (size_t)blk * 128;
  const int wv = t >> 6, lane = t & 63;
  const short8v* w1f = (const short8v*)w1p;
  const short8v* w2f = (const short8v*)w2p;

  // issue W1 top-half fragment loads (16) — latency hidden under staging
  short8v w1r[16];
  #pragma unroll
  for (int ot = 0; ot < 8; ++ot)
    #pragma unroll
    for (int kc = 0; kc < 2; ++kc)
      w1r[ot * 2 + kc] = w1f[(ot * 4 + kc) * 64 + lane];

  // stage Xw (c=0..63): bf16 bit-copy from weighted
  #pragma unroll
  for (int q = 0; q < 4; ++q) {
    const int chunk = q * 256 + t;
    const int m = chunk >> 3, a = chunk & 7;
    const uint4 pk = *(const uint4*)&wbf[(M0 + m) * 64 + a * 8];
    const int kc = a >> 2, hi = a & 3;
    const int u = ((m >> 4) * 4 + kc) * 64 + hi * 16 + (m & 15);
    *(uint4*)&SB[SBU(u) * 8] = pk;
  }
  // stage hO (bf16) rows for this tile's n-range: 768 uints
  const int nmin = ml0 / 15;
  #pragma unroll
  for (int q = 0; q < 3; ++q) {
    const int idx = q * 256 + t;  // < 768
    const int row = idx >> 6, pr = idx & 63;
    int n = nmin + row;
    if (n > 4095) n = 4095;
    ((unsigned*)hOS)[idx] = ((const unsigned*)(hOb + ((size_t)b * 4096 + n) * 128))[pr];
  }
  __syncthreads();

  // this wave's Xw B-fragments (K=64: kc 0,1)
  short8v xf[4];
  #pragma unroll
  for (int mt = 0; mt < 2; ++mt)
    #pragma unroll
    for (int kc = 0; kc < 2; ++kc) {
      const int u = ((wv * 2 + mt) * 4 + kc) * 64 + lane;
      xf[mt * 2 + kc] = *(const short8v*)&SB[SBU(u) * 8];
    }

  const int rb = (lane >> 4) * 4;
  const int dnA = (ml0 + wv * 32 + (lane & 15)) / 15 - nmin;
  const int dnB = (ml0 + wv * 32 + 16 + (lane & 15)) / 15 - nmin;
  f32x4 acc[8][2];
  #pragma unroll
  for (int ot = 0; ot < 8; ++ot) {
    const uint2 pa = *(const uint2*)&hOS[dnA * 128 + ot * 16 + rb];
    const uint2 pb = *(const uint2*)&hOS[dnB * 128 + ot * 16 + rb];
    acc[ot][0] = (f32x4){bflo(pa.x), bfhi(pa.x), bflo(pa.y), bfhi(pa.y)};
    acc[ot][1] = (f32x4){bflo(pb.x), bfhi(pb.x), bflo(pb.y), bfhi(pb.y)};
  }
  // issue first half of W2 (ot 0..3) — latency covered by stage-1 MFMAs
  short8v w2a[16];
  #pragma unroll
  for (int i = 0; i < 16; ++i) w2a[i] = w2f[i * 64 + lane];

  // stage 1: acc += W1a @ Xw  (K=64)
  #pragma unroll
  for (int kc = 0; kc < 2; ++kc) {
    #pragma unroll
    for (int ot = 0; ot < 8; ++ot) {
      acc[ot][0] = __builtin_amdgcn_mfma_f32_16x16x32_bf16(w1r[ot * 2 + kc], xf[kc],     acc[ot][0], 0, 0, 0);
      acc[ot][1] = __builtin_amdgcn_mfma_f32_16x16x32_bf16(w1r[ot * 2 + kc], xf[2 + kc], acc[ot][1], 0, 0, 0);
    }
  }
  // H epilogue (relu; b1 folded into hO) -> wave's own SB region
  #pragma unroll
  for (int ot = 0; ot < 8; ++ot) {
    const int o0 = ot * 16 + rb;
    const int kc = o0 >> 5, hi = (o0 >> 3) & 3, j0 = o0 & 7;
    #pragma unroll
    for (int mt = 0; mt < 2; ++mt) {
      const f32x4 h = acc[ot][mt];
      const float h0 = fmaxf(h[0], 0.f);
      const float h1 = fmaxf(h[1], 0.f);
      const float h2 = fmaxf(h[2], 0.f);
      const float h3 = fmaxf(h[3], 0.f);
      const int u = ((wv * 2 + mt) * 4 + kc) * 64 + hi * 16 + (lane & 15);
      uint2 pk;
      pk.x = pkbf(h0, h1);
      pk.y = pkbf(h2, h3);
      *(uint2*)&SB[SBU(u) * 8 + j0] = pk;
    }
  }
  // issue second half of W2 (ot 4..7) — latency covered by hf reads + stage-2a
  short8v w2b[16];
  #pragma unroll
  for (int i = 0; i < 16; ++i) w2b[i] = w2f[(16 + i) * 64 + lane];

  // read H fragments (K=128)
  short8v hf[8];
  #pragma unroll
  for (int mt = 0; mt < 2; ++mt)
    #pragma unroll
    for (int kc = 0; kc < 4; ++kc) {
      const int u = ((wv * 2 + mt) * 4 + kc) * 64 + lane;
      hf[mt * 4 + kc] = *(const short8v*)&SB[SBU(u) * 8];
    }
  // stage 2a: ot 0..3 with w2a
  #pragma unroll
  for (int ot = 0; ot < 8; ++ot) {
    acc[ot][0] = (f32x4){0.f, 0.f, 0.f, 0.f};
    acc[ot][1] = (f32x4){0.f, 0.f, 0.f, 0.f};
  }
  #pragma unroll
  for (int kc = 0; kc < 4; ++kc) {
    #pragma unroll
    for (int ot = 0; ot < 4; ++ot) {
      acc[ot][0] = __builtin_amdgcn_mfma_f32_16x16x32_bf16(w2a[ot * 4 + kc], hf[kc],     acc[ot][0], 0, 0, 0);
      acc[ot][1] = __builtin_amdgcn_mfma_f32_16x16x32_bf16(w2a[ot * 4 + kc], hf[4 + kc], acc[ot][1], 0, 0, 0);
    }
  }
  // stage 2b: ot 4..7 with w2b
  #pragma unroll
  for (int kc = 0; kc < 4; ++kc) {
    #pragma unroll
    for (int ot = 4; ot < 8; ++ot) {
      acc[ot][0] = __builtin_amdgcn_mfma_f32_16x16x32_bf16(w2b[(ot - 4) * 4 + kc], hf[kc],     acc[ot][0], 0, 0, 0);
      acc[ot][1] = __builtin_amdgcn_mfma_f32_16x16x32_bf16(w2b[(ot - 4) * 4 + kc], hf[4 + kc], acc[ot][1], 0, 0, 0);
    }
  }
  // F epilogue -> global (direct strided stores)
  float* fp0 = fuse + (size_t)b * 128 * 61440 + ml0 + wv * 32 + (lane & 15);
  #pragma unroll
  for (int ot = 0; ot < 8; ++ot) {
    const int o0 = ot * 16 + rb;
    const float4 b2 = *(const float4*)&f2_b[o0];
    const float bv[4] = {b2.x, b2.y, b2.z, b2.w};
    #pragma unroll
    for (int mt = 0; mt < 2; ++mt) {
      const f32x4 vacc = acc[ot][mt];
      #pragma unroll
      for (int r = 0; r < 4; ++r)
        fp0[(size_t)(o0 + r) * 61440 + mt * 16] = fmaxf(vacc[r] + bv[r], 0.f);
    }
  }
}

extern "C" void kernel_launch(void* const* d_in, const int* in_sizes, int n_in,
                              void* d_out, int out_size, void* d_ws, size_t ws_size,
                              hipStream_t stream) {
  const float* pos     = (const float*)d_in[0];
  const float* feat    = (const float*)d_in[1];
  const float* kp_pos  = (const float*)d_in[2];
  const float* cb_w    = (const float*)d_in[3];
  const float* cb_b    = (const float*)d_in[4];
  const float* kpw     = (const float*)d_in[5];
  const float* kp_bias = (const float*)d_in[6];
  const float* ce_w    = (const float*)d_in[7];
  const float* ce_b    = (const float*)d_in[8];
  const float* f1_w    = (const float*)d_in[9];
  const float* f1_b    = (const float*)d_in[10];
  const float* f2_w    = (const float*)d_in[11];
  const float* f2_b    = (const float*)d_in[12];
  float* out = (float*)d_out;
  char* ws = (char*)d_ws;
  int*   idx_ws   = (int*)(ws + OFF_IDX);
  float* feat0    = (float*)(ws + OFF_FEAT0);
  unsigned short* wbf  = (unsigned short*)(ws + OFF_WEIGHTED);
  unsigned short* hOb  = (unsigned short*)(ws + OFF_HO);
  unsigned short* w1p  = (unsigned short*)(ws + OFF_W1P);
  unsigned short* w2p  = (unsigned short*)(ws + OFF_W2P);
  unsigned short* kpwp = (unsigned short*)(ws + OFF_KPWP);

  k012<<<8562, 256, 0, stream>>>(pos, feat, cb_w, cb_b, f1_w, f2_w, kpw, kp_pos,
                                 idx_ws, feat0, w1p, w2p, kpwp, out + OUT_OFF_KP);
  k3_weighted<<<4096, 256, 0, stream>>>(pos, idx_ws, feat0, kp_pos, wbf);
  k45<<<256, 256, 0, stream>>>(wbf, kpwp, kp_bias, ce_w, ce_b, feat, w1p, f1_b,
                               out + OUT_OFF_OUT, hOb);
  k6_fuse<<<1920, 256, 0, stream>>>(wbf, hOb, w1p, w2p, f2_b, out + OUT_OFF_FUSE);
}